// Round 2
// baseline (211.970 us; speedup 1.0000x reference)
//
#include <hip/hip_runtime.h>
#include <math.h>

// B=4, T=512, IDIM=128, HDIM=1024, CDIM=256
#define NROWS   2048
#define NITER   4
#define IGNORE_OUT 10000.0f

// ---------- block reduction helpers (256 threads = 4 waves). ALL threads must call. ----------

__device__ __forceinline__ float blkSum(float v, float* red){
  #pragma unroll
  for (int o = 32; o; o >>= 1) v += __shfl_down(v, o, 64);
  int lane = threadIdx.x & 63, wid = threadIdx.x >> 6;
  __syncthreads();                 // protect red reuse from previous reduction
  if (lane == 0) red[wid] = v;
  __syncthreads();
  return red[0] + red[1] + red[2] + red[3];
}

__device__ __forceinline__ float blkMax(float v, float* red){
  #pragma unroll
  for (int o = 32; o; o >>= 1) v = fmaxf(v, __shfl_down(v, o, 64));
  int lane = threadIdx.x & 63, wid = threadIdx.x >> 6;
  __syncthreads();
  if (lane == 0) red[wid] = v;
  __syncthreads();
  return fmaxf(fmaxf(red[0], red[1]), fmaxf(red[2], red[3]));
}

// first-occurrence argmax (numpy semantics): max value, ties -> smallest index
__device__ __forceinline__ int blkArgmaxFirst(float v, int idx, float* redv, int* redi){
  #pragma unroll
  for (int o = 32; o; o >>= 1){
    float ov = __shfl_down(v,   o, 64);
    int   oi = __shfl_down(idx, o, 64);
    if (ov > v || (ov == v && oi < idx)) { v = ov; idx = oi; }
  }
  int lane = threadIdx.x & 63, wid = threadIdx.x >> 6;
  __syncthreads();
  if (lane == 0){ redv[wid] = v; redi[wid] = idx; }
  __syncthreads();
  float bv = redv[0]; int bi = redi[0];
  #pragma unroll
  for (int w = 1; w < 4; ++w){
    float ov = redv[w]; int oi = redi[w];
    if (ov > bv || (ov == bv && oi < bi)) { bv = ov; bi = oi; }
  }
  return bi;
}

// ---------- prep kernel: buildM (blocks 0..511) + bias (512..515) + acc zero (516) ----------
// Mt layout: Mt[i*16384 + d*128 + o]
__global__ __launch_bounds__(256)
void prepK(const float* __restrict__ w1, const float* __restrict__ b1,
           const float* __restrict__ w2, const float* __restrict__ b2,
           float* __restrict__ Mt, float* __restrict__ biasT, float* __restrict__ acc){
  __shared__ float part[256];
  const int blk = blockIdx.x;
  const int u = threadIdx.x;
  if (blk < 512){
    int i = blk >> 7, o = blk & 127;
    int d = u & 127, ch = u >> 7;
    const float* w1p = w1 + (i * 256 + ch * 128) * 128 + d;   // coalesced over d
    const float* w2p = w2 + o * 1024 + i * 256 + ch * 128;    // uniform (scalar)
    float a = 0.f;
    #pragma unroll 16
    for (int c = 0; c < 128; ++c) a = fmaf(w1p[c * 128], w2p[c], a);
    part[u] = a;
    __syncthreads();
    if (u < 128) Mt[(i * 128 + u) * 128 + o] = part[u] + part[u + 128];
  } else if (blk < 516){
    int i = blk - 512;
    if (u < 128){
      const float* w2p = w2 + u * 1024 + i * 256;
      const float* b1p = b1 + i * 256;
      float a = b2[u];
      #pragma unroll 8
      for (int c = 0; c < 256; ++c) a = fmaf(b1p[c], w2p[c], a);
      biasT[i * 128 + u] = a;
    }
  } else {
    if (u < 2) acc[u] = 0.f;
  }
}

// ---------- main kernel: one block per (b,t) row, 256 threads ----------
__global__ __launch_bounds__(256, 8)
void mainK(const float* __restrict__ x, const float* __restrict__ y,
           const float* __restrict__ Mt, const float* __restrict__ biasT,
           float* __restrict__ acc){
  __shared__ alignas(16) float xr[128];   // x_res
  __shared__ float yd[384];               // yd[k] = y_res[k & 127] (only [128,384) used)
  __shared__ float xatt[128];             // x_attn
  __shared__ float pn1[256];              // corr partials (reused as MLP partials)
  __shared__ float pnt[256];
  __shared__ float pref[128];             // inclusive prefix of xr^2
  __shared__ float wtot[2];
  __shared__ float redf[4];
  __shared__ int   redi[4];

  const int u    = threadIdx.x;
  const int lane = u & 63;
  const int wid  = u >> 6;                // wave id 0..3
  const int t    = u & 127;               // shift-pair id
  const int h    = u >> 7;                // j-range half
  const int jb   = h * 64;
  const long base = (long)blockIdx.x * 128;

  float lossAcc = 0.f, cnt = 0.f;
  bool  maskv = false;
  float xv = 0.f, yv = 0.f;               // registers mirror xr[u], y_res[u]
  if (u < 128){
    xv = x[base + u];
    yv = y[base + u];
    xr[u] = xv;
    maskv = (yv == IGNORE_OUT);
    cnt = maskv ? 0.f : 1.f;
  }
  __syncthreads();

  for (int i = 0; i < NITER; ++i){
    // ---- Phase A: prefix scan of xr^2 (for window norms), ||y||^2, build yd ----
    float v = (u < 128) ? xv * xv : 0.f;
    #pragma unroll
    for (int o2 = 1; o2 < 64; o2 <<= 1){
      float tv = __shfl_up(v, o2, 64);
      if (lane >= o2) v += tv;
    }
    __syncthreads();                       // protect wtot/yd reuse from previous iter
    if (u < 128 && lane == 63) wtot[u >> 6] = v;
    if (u < 128){ yd[128 + u] = yv; yd[256 + u] = yv; }
    __syncthreads();
    float total = wtot[0] + wtot[1];
    if (u >= 64 && u < 128) v += wtot[0];
    if (u < 128) pref[u] = v;
    float ny2 = blkSum((u < 128) ? yv * yv : 0.f, redf);  // barriers make pref/yd visible

    // ---- Phase B: balanced correlation. Thread (t,h): shifts t and t+128, j in [64h,64h+64) ----
    // num(t)      = sum_{j<=t} yd[255-t+j]*xr[j]      (shift t)
    // num(t+128)  = sum_{j> t} yd[255-t+j]*xr[j]      (shift t+128)
    {
      const float* ydp = yd + (255 - t);
      float n1 = 0.f, nt = 0.f;
      if (wid == 1){                       // t in [64,127], j in [0,64): j<=t always
        #pragma unroll 4
        for (int j = 0; j < 64; j += 4){
          float4 x4 = *(const float4*)&xr[j];
          n1 = fmaf(ydp[j + 0], x4.x, n1);
          n1 = fmaf(ydp[j + 1], x4.y, n1);
          n1 = fmaf(ydp[j + 2], x4.z, n1);
          n1 = fmaf(ydp[j + 3], x4.w, n1);
        }
        nt = n1;
      } else if (wid == 2){                // t in [0,63], j in [64,128): j>t always
        #pragma unroll 4
        for (int j = 64; j < 128; j += 4){
          float4 x4 = *(const float4*)&xr[j];
          nt = fmaf(ydp[j + 0], x4.x, nt);
          nt = fmaf(ydp[j + 1], x4.y, nt);
          nt = fmaf(ydp[j + 2], x4.z, nt);
          nt = fmaf(ydp[j + 3], x4.w, nt);
        }
      } else {                             // boundary j==t inside this wave's range
        #pragma unroll 4
        for (int j = jb; j < jb + 64; j += 4){
          float4 x4 = *(const float4*)&xr[j];
          float p;
          p = ydp[j + 0] * x4.x; nt += p; n1 += (j + 0 <= t) ? p : 0.f;
          p = ydp[j + 1] * x4.y; nt += p; n1 += (j + 1 <= t) ? p : 0.f;
          p = ydp[j + 2] * x4.z; nt += p; n1 += (j + 2 <= t) ? p : 0.f;
          p = ydp[j + 3] * x4.w; nt += p; n1 += (j + 3 <= t) ? p : 0.f;
        }
      }
      pn1[u] = n1; pnt[u] = nt;
    }
    __syncthreads();

    // ---- Phase C: cosine sims + first-max argmax over 255 shifts ----
    float simv = -INFINITY; int sidx = 1000 + u;
    if (u < 128){
      float a1 = pn1[u] + pn1[u + 128];            // num(shift u)
      float at = pnt[u] + pnt[u + 128];
      float a2 = at - a1;                          // num(shift u+128)
      float nY  = sqrtf(ny2);
      float nx1 = pref[u];
      float nx2 = fmaxf(total - pref[u], 0.f);
      float den1 = nY * sqrtf(nx1);
      float den2 = nY * sqrtf(nx2);
      float s1 = (den1 == 0.f) ? 0.f : a1 / den1;
      float s2 = (den2 == 0.f) ? 0.f : a2 / den2;
      if (u == 127) s2 = -INFINITY;                // shift 255 doesn't exist
      if (s1 >= s2){ simv = s1; sidx = u; } else { simv = s2; sidx = u + 128; }
    }
    int sstar = blkArgmaxFirst(simv, sidx, redf, redi);

    // ---- Phase D: x_aug + detached softmax attention ----
    float xa = 0.f, z = -INFINITY;
    if (u < 128){
      int j = sstar + u - 127;
      xa = ((unsigned)j < 128u) ? xr[j] : 0.f;
      z  = xa * yv;
    }
    float mz = blkMax(z, redf);
    float e  = (u < 128) ? expf(z - mz) : 0.f;
    float se = blkSum(e, redf);
    if (u < 128) xatt[u] = xa * (e / se);
    __syncthreads();                               // xatt visible; xr reads done before writes

    // ---- Phase E: reverse shift, x_res update (register + LDS) ----
    if (u < 128){
      int j2 = u + 127 - sstar;
      float xe = ((unsigned)j2 < 128u) ? xatt[j2] : 0.f;
      xv -= xe;
      xr[u] = xv;
    }

    // ---- Phase F: MLP via M_i: y_ele[o] = sum_d Mt[i][d][o] * xatt[d] ----
    {
      const float* Mi = Mt + i * 16384 + t + jb * 128;
      float a2 = 0.f;
      #pragma unroll 16
      for (int d = 0; d < 64; ++d)
        a2 = fmaf(Mi[d * 128], xatt[jb + d], a2);
      pn1[u] = a2;                                 // reuse pn1 (old reads done at C)
    }
    __syncthreads();

    // ---- Phase G: loss + y_res update ----
    if (u < 128){
      float ye   = pn1[u] + pn1[u + 128] + biasT[i * 128 + u];
      float diff = ye - yv;
      if (!maskv) lossAcc = fmaf(diff, diff, lossAcc);
      yv = -diff;                                  // y_res - y_ele
    }
    __syncthreads();                               // xr/pn1 writes drained before next iter
  }

  float tot  = blkSum(lossAcc, redf);
  float totc = blkSum(cnt, redf);
  if (u == 0){
    atomicAdd(&acc[0], tot);
    atomicAdd(&acc[1], totc);
  }
}

// ---------- finalize ----------
__global__ void finalize(const float* __restrict__ acc, float* __restrict__ out){
  if (threadIdx.x == 0 && blockIdx.x == 0)
    out[0] = acc[0] / ((float)NITER * acc[1]);
}

extern "C" void kernel_launch(void* const* d_in, const int* in_sizes, int n_in,
                              void* d_out, int out_size, void* d_ws, size_t ws_size,
                              hipStream_t stream){
  const float* x  = (const float*)d_in[0];
  const float* y  = (const float*)d_in[1];
  const float* w1 = (const float*)d_in[2];
  const float* b1 = (const float*)d_in[3];
  const float* w2 = (const float*)d_in[4];
  const float* b2 = (const float*)d_in[5];
  float* out = (float*)d_out;

  float* accp  = (float*)d_ws;
  float* Mt    = (float*)((char*)d_ws + 256);
  float* biasT = (float*)((char*)d_ws + 256 + 4 * 128 * 128 * sizeof(float));

  prepK<<<517, 256, 0, stream>>>(w1, b1, w2, b2, Mt, biasT, accp);
  mainK<<<NROWS, 256, 0, stream>>>(x, y, Mt, biasT, accp);
  finalize<<<1, 64, 0, stream>>>(accp, out);
}

// Round 3
// 178.861 us; speedup vs baseline: 1.1851x; 1.1851x over previous
//
#include <hip/hip_runtime.h>
#include <math.h>

// B=4, T=512, IDIM=128, HDIM=1024, CDIM=256
#define NROWS   2048
#define NITER   4
#define IGNORE_OUT 10000.0f

// ---------- prep kernel ----------
// blocks 0..511 : Mt2[i][o][d] = M_i[d][o] = sum_c w1[c,d] * w2[o,c]   (i=blk>>7, o=blk&127, d=thread)
// blocks 512..515 : biasT[i][o] = b2[o] + sum_c b1[c] * w2[o,c]
// block 516 : zero the accumulators
__global__ __launch_bounds__(128)
void prepK(const float* __restrict__ w1, const float* __restrict__ b1,
           const float* __restrict__ w2, const float* __restrict__ b2,
           float* __restrict__ Mt2, float* __restrict__ biasT, float* __restrict__ acc){
  const int blk = blockIdx.x;
  const int u = threadIdx.x;
  if (blk < 512){
    int i = blk >> 7, o = blk & 127;
    const float* w1p = w1 + (i * 256) * 128 + u;   // coalesced over d=u
    const float* w2p = w2 + o * 1024 + i * 256;    // thread-uniform (scalar loads)
    float a = 0.f;
    #pragma unroll 16
    for (int c = 0; c < 256; ++c) a = fmaf(w1p[c * 128], w2p[c], a);
    Mt2[(i * 128 + o) * 128 + u] = a;              // d-fast layout, coalesced store
  } else if (blk < 516){
    int i = blk - 512;
    const float* w2p = w2 + u * 1024 + i * 256;
    const float* b1p = b1 + i * 256;
    float a = b2[u];
    #pragma unroll 8
    for (int c = 0; c < 256; ++c) a = fmaf(b1p[c], w2p[c], a);
    biasT[i * 128 + u] = a;
  } else {
    if (u < 2) acc[u] = 0.f;
  }
}

// ---------- main kernel: ONE WAVE per row. Lane l owns elements {l, l+64} and
// shift-pairs (l, l+128) and (l+64, l+192). All reductions are wave shuffles. ----------
__global__ __launch_bounds__(64, 2)
void mainK(const float* __restrict__ x, const float* __restrict__ y,
           const float* __restrict__ Mt2, const float* __restrict__ biasT,
           float* __restrict__ acc){
  __shared__ alignas(16) float xr[128];    // x_res
  __shared__ alignas(16) float xatt[128];  // x_attn
  __shared__ float yd[384];                // yd[128+k] = yd[256+k] = y_res[k]

  const int l = threadIdx.x;               // 0..63
  const long base = (long)blockIdx.x * 128;

  float xv0 = x[base + l],      xv1 = x[base + 64 + l];
  float yv0 = y[base + l],      yv1 = y[base + 64 + l];
  const bool m0 = (yv0 == IGNORE_OUT), m1 = (yv1 == IGNORE_OUT);
  float cnt = (m0 ? 0.f : 1.f) + (m1 ? 0.f : 1.f);
  float lossAcc = 0.f;

  xr[l] = xv0; xr[64 + l] = xv1;
  yd[128 + l] = yv0; yd[192 + l] = yv1;
  yd[256 + l] = yv0; yd[320 + l] = yv1;
  __syncthreads();                         // single wave: just a waitcnt drain

  for (int i = 0; i < NITER; ++i){
    // ---- wave prefix-scan of xr^2 -> window norms (registers only) ----
    float s0 = xv0 * xv0, s1 = xv1 * xv1;
    #pragma unroll
    for (int o2 = 1; o2 < 64; o2 <<= 1){
      float t0 = __shfl_up(s0, o2, 64);
      float t1 = __shfl_up(s1, o2, 64);
      if (l >= o2){ s0 += t0; s1 += t1; }
    }
    float tot0  = __shfl(s0, 63, 64);
    float prefA = s0;                      // pref[l]
    float prefB = s1 + tot0;               // pref[l+64]
    float total = __shfl(s1, 63, 64) + tot0;

    // ---- ||y_res||^2 (butterfly sum) ----
    float ny = yv0 * yv0 + yv1 * yv1;
    #pragma unroll
    for (int o2 = 32; o2; o2 >>= 1) ny += __shfl_xor(ny, o2, 64);
    float nY = sqrtf(ny);

    // ---- balanced Toeplitz correlation ----
    // pair A (t=l):    num(l)     = sum_{j<=l}    ydpA[j]*xr[j];  num(l+128) = rest
    // pair B (t=l+64): num(l+64)  = sum_{j<=l+64} ydpB[j]*xr[j];  num(l+192) = rest
    const float* ydpA = yd + (255 - l);
    const float* ydpB = yd + (191 - l);
    float ntA = 0.f, n1A = 0.f, ntB = 0.f, n1B = 0.f;
    #pragma unroll 4
    for (int j4 = 0; j4 < 64; j4 += 4){    // j <= 63 < l+64 always: B fully in n1B
      float4 x4 = *(const float4*)&xr[j4];
      float xx[4] = {x4.x, x4.y, x4.z, x4.w};
      #pragma unroll
      for (int e = 0; e < 4; ++e){
        int j = j4 + e;
        float pA = ydpA[j] * xx[e];
        float pB = ydpB[j] * xx[e];
        ntA += pA; n1A += (j <= l) ? pA : 0.f;
        ntB += pB; n1B += pB;
      }
    }
    #pragma unroll 4
    for (int j4 = 64; j4 < 128; j4 += 4){  // j > l always for pair A
      float4 x4 = *(const float4*)&xr[j4];
      float xx[4] = {x4.x, x4.y, x4.z, x4.w};
      #pragma unroll
      for (int e = 0; e < 4; ++e){
        int j = j4 + e;
        float pA = ydpA[j] * xx[e];
        float pB = ydpB[j] * xx[e];
        ntA += pA;
        ntB += pB; n1B += (j - 64 <= l) ? pB : 0.f;
      }
    }

    // ---- cosine sims, local first-max over 4 candidates, wave first-max ----
    float bv; int bi;
    {
      float numA1 = n1A, numA2 = ntA - n1A;
      float numB1 = n1B, numB2 = ntB - n1B;
      float dA1 = nY * sqrtf(prefA);
      float dB1 = nY * sqrtf(prefB);
      float dA2 = nY * sqrtf(fmaxf(total - prefA, 0.f));
      float dB2 = nY * sqrtf(fmaxf(total - prefB, 0.f));
      float sA1 = (dA1 == 0.f) ? 0.f : numA1 / dA1;   // shift l
      float sB1 = (dB1 == 0.f) ? 0.f : numB1 / dB1;   // shift l+64
      float sA2 = (dA2 == 0.f) ? 0.f : numA2 / dA2;   // shift l+128
      float sB2 = (dB2 == 0.f) ? 0.f : numB2 / dB2;   // shift l+192
      if (l == 63) sB2 = -INFINITY;                   // shift 255 doesn't exist
      bv = sA1; bi = l;                               // index-ascending, strict >
      if (sB1 > bv){ bv = sB1; bi = l + 64;  }
      if (sA2 > bv){ bv = sA2; bi = l + 128; }
      if (sB2 > bv){ bv = sB2; bi = l + 192; }
    }
    #pragma unroll
    for (int o2 = 1; o2 < 64; o2 <<= 1){
      float ov = __shfl_xor(bv, o2, 64);
      int   oi = __shfl_xor(bi, o2, 64);
      if (ov > bv || (ov == bv && oi < bi)){ bv = ov; bi = oi; }
    }
    const int sstar = bi;                  // all lanes agree

    // ---- x_aug + detached softmax attention (registers + shuffles) ----
    int j0 = sstar + l - 127, j1 = j0 + 64;
    float xa0 = ((unsigned)j0 < 128u) ? xr[j0] : 0.f;
    float xa1 = ((unsigned)j1 < 128u) ? xr[j1] : 0.f;
    float z0 = xa0 * yv0, z1 = xa1 * yv1;
    float mz = fmaxf(z0, z1);
    #pragma unroll
    for (int o2 = 32; o2; o2 >>= 1) mz = fmaxf(mz, __shfl_xor(mz, o2, 64));
    float e0 = expf(z0 - mz), e1 = expf(z1 - mz);
    float se = e0 + e1;
    #pragma unroll
    for (int o2 = 32; o2; o2 >>= 1) se += __shfl_xor(se, o2, 64);
    float w0 = xa0 * (e0 / se), w1v = xa1 * (e1 / se);
    xatt[l] = w0; xatt[64 + l] = w1v;
    __syncthreads();                       // xatt visible; all xr reads above done

    // ---- x_ele (reverse shift) + x_res update ----
    int k0 = l + 127 - sstar, k1 = k0 + 64;
    xv0 -= ((unsigned)k0 < 128u) ? xatt[k0] : 0.f;
    xv1 -= ((unsigned)k1 < 128u) ? xatt[k1] : 0.f;
    xr[l] = xv0; xr[64 + l] = xv1;

    // ---- MLP: y_ele[o] = sum_d Mt2[i][o][d] * xatt[d], o in {l, l+64} ----
    const float* MiA = Mt2 + (i * 128 + l) * 128;
    const float* MiB = MiA + 64 * 128;
    float aA = 0.f, aB = 0.f;
    #pragma unroll 4
    for (int d4 = 0; d4 < 128; d4 += 4){
      float4 xa4 = *(const float4*)&xatt[d4];   // wave-uniform broadcast
      float4 A4  = *(const float4*)&MiA[d4];    // global b128 (L2-resident)
      float4 B4  = *(const float4*)&MiB[d4];
      aA = fmaf(A4.x, xa4.x, aA); aA = fmaf(A4.y, xa4.y, aA);
      aA = fmaf(A4.z, xa4.z, aA); aA = fmaf(A4.w, xa4.w, aA);
      aB = fmaf(B4.x, xa4.x, aB); aB = fmaf(B4.y, xa4.y, aB);
      aB = fmaf(B4.z, xa4.z, aB); aB = fmaf(B4.w, xa4.w, aB);
    }
    float ye0 = aA + biasT[i * 128 + l];
    float ye1 = aB + biasT[i * 128 + 64 + l];
    float d0 = ye0 - yv0, d1 = ye1 - yv1;
    if (!m0) lossAcc = fmaf(d0, d0, lossAcc);
    if (!m1) lossAcc = fmaf(d1, d1, lossAcc);
    yv0 = -d0; yv1 = -d1;                  // y_res -= y_ele
    yd[128 + l] = yv0; yd[192 + l] = yv1;
    yd[256 + l] = yv0; yd[320 + l] = yv1;
    __syncthreads();                       // xr/yd stores drained before next iter
  }

  // ---- loss reduction + atomics ----
  #pragma unroll
  for (int o2 = 32; o2; o2 >>= 1){
    lossAcc += __shfl_xor(lossAcc, o2, 64);
    cnt     += __shfl_xor(cnt,     o2, 64);
  }
  if (l == 0){
    atomicAdd(&acc[0], lossAcc);
    atomicAdd(&acc[1], cnt);
  }
}

// ---------- finalize ----------
__global__ void finalize(const float* __restrict__ acc, float* __restrict__ out){
  if (threadIdx.x == 0 && blockIdx.x == 0)
    out[0] = acc[0] / ((float)NITER * acc[1]);
}

extern "C" void kernel_launch(void* const* d_in, const int* in_sizes, int n_in,
                              void* d_out, int out_size, void* d_ws, size_t ws_size,
                              hipStream_t stream){
  const float* x  = (const float*)d_in[0];
  const float* y  = (const float*)d_in[1];
  const float* w1 = (const float*)d_in[2];
  const float* b1 = (const float*)d_in[3];
  const float* w2 = (const float*)d_in[4];
  const float* b2 = (const float*)d_in[5];
  float* out = (float*)d_out;

  float* accp  = (float*)d_ws;
  float* Mt2   = (float*)((char*)d_ws + 256);
  float* biasT = (float*)((char*)d_ws + 256 + 4 * 128 * 128 * sizeof(float));

  prepK<<<517, 128, 0, stream>>>(w1, b1, w2, b2, Mt2, biasT, accp);
  mainK<<<NROWS, 64, 0, stream>>>(x, y, Mt2, biasT, accp);
  finalize<<<1, 64, 0, stream>>>(accp, out);
}